// Round 1
// baseline (90.737 us; speedup 1.0000x reference)
//
#include <hip/hip_runtime.h>
#include <math.h>

struct c2 { float re, im; };

__device__ __forceinline__ c2 cmul(c2 a, c2 b) {
    return { a.re * b.re - a.im * b.im, a.re * b.im + a.im * b.re };
}

// One block per h (2048 blocks, 256 threads). Each thread produces 4 consecutive
// l values per iteration as a float4 store, striding by 1024 elements between
// iterations. K[h,n,l] = A_bar^l is generated by complex-multiply recurrence:
//   within group: multiply by A_bar; between groups: multiply by A_bar^1024.
// cb = C * B_bar is folded into the running state so out = sum_n Re(k_n).
__global__ __launch_bounds__(256) void pmsn_ssm_kernel(
    const float* __restrict__ log_dt,
    const float* __restrict__ log_A_real,
    const float* __restrict__ A_imag,
    const float* __restrict__ VBr, const float* __restrict__ VBi,
    const float* __restrict__ CVr, const float* __restrict__ CVi,
    float* __restrict__ out, int L)
{
    const int h    = blockIdx.x;
    const int lane = threadIdx.x;           // 0..255
    const float dt = expf(log_dt[h]);

    c2 k[4];      // running cb * A_bar^l
    c2 Ab[4];     // A_bar
    c2 R[4];      // A_bar^1024 (iteration stride)
    c2 cb[4];     // C * B_bar (kept for scalar tail)
    float adr[4], adi[4];

    const float l0 = (float)(4 * lane);

#pragma unroll
    for (int n = 0; n < 4; ++n) {
        const int idx = h * 4 + n;
        const float ar = -expf(log_A_real[idx]);
        const float ai = A_imag[idx];
        adr[n] = ar * dt;
        adi[n] = ai * dt;

        float s, c;
        const float e = expf(adr[n]);
        sincosf(adi[n], &s, &c);
        const c2 Abar = { e * c, e * s };
        Ab[n] = Abar;

        // B_bar = (A_bar - 1) * B / A   (complex divide by A = multiply by conj/|A|^2)
        const c2 B   = { VBr[idx], VBi[idx] };
        const c2 num = cmul({ Abar.re - 1.0f, Abar.im }, B);
        const float inv = 1.0f / (ar * ar + ai * ai);
        const c2 Bbar = { (num.re * ar + num.im * ai) * inv,
                          (num.im * ar - num.re * ai) * inv };
        const c2 C = { CVr[idx], CVi[idx] };
        cb[n] = cmul(C, Bbar);

        // k = cb * exp(adt * l0)
        const float el = expf(adr[n] * l0);
        sincosf(adi[n] * l0, &s, &c);
        k[n] = cmul(cb[n], { el * c, el * s });

        // ratio = exp(adt * 1024)
        const float er = expf(adr[n] * 1024.0f);
        sincosf(adi[n] * 1024.0f, &s, &c);
        R[n] = { er * c, er * s };
    }

    float4* outv = (float4*)(out + (size_t)h * (size_t)L);
    const int nIter = L >> 10;              // groups of 1024 elements

    int vIdx = lane;                        // float4 index
    for (int it = 0; it < nIter; ++it, vIdx += 256) {
        float4 v;
        c2 t[4];
        v.x = k[0].re + k[1].re + k[2].re + k[3].re;
#pragma unroll
        for (int n = 0; n < 4; ++n) t[n] = cmul(k[n], Ab[n]);
        v.y = t[0].re + t[1].re + t[2].re + t[3].re;
#pragma unroll
        for (int n = 0; n < 4; ++n) t[n] = cmul(t[n], Ab[n]);
        v.z = t[0].re + t[1].re + t[2].re + t[3].re;
#pragma unroll
        for (int n = 0; n < 4; ++n) t[n] = cmul(t[n], Ab[n]);
        v.w = t[0].re + t[1].re + t[2].re + t[3].re;

        outv[vIdx] = v;

#pragma unroll
        for (int n = 0; n < 4; ++n) k[n] = cmul(k[n], R[n]);
    }

    // Scalar tail for L not a multiple of 1024 (not hit for L=4096).
    for (int l = (L & ~1023) + lane; l < L; l += 256) {
        float acc = 0.0f;
        const float fl = (float)l;
#pragma unroll
        for (int n = 0; n < 4; ++n) {
            float s, c;
            const float e = expf(adr[n] * fl);
            sincosf(adi[n] * fl, &s, &c);
            const c2 kk = cmul(cb[n], { e * c, e * s });
            acc += kk.re;
        }
        out[(size_t)h * (size_t)L + l] = acc;
    }
}

extern "C" void kernel_launch(void* const* d_in, const int* in_sizes, int n_in,
                              void* d_out, int out_size, void* d_ws, size_t ws_size,
                              hipStream_t stream) {
    const float* log_dt     = (const float*)d_in[0];
    const float* log_A_real = (const float*)d_in[1];
    const float* A_imag     = (const float*)d_in[2];
    const float* VBr        = (const float*)d_in[3];
    const float* VBi        = (const float*)d_in[4];
    const float* CVr        = (const float*)d_in[5];
    const float* CVi        = (const float*)d_in[6];
    float* out = (float*)d_out;

    const int H = in_sizes[0];              // 2048
    const int L = out_size / H;             // 4096

    pmsn_ssm_kernel<<<H, 256, 0, stream>>>(log_dt, log_A_real, A_imag,
                                           VBr, VBi, CVr, CVi, out, L);
}